// Round 4
// baseline (1414.152 us; speedup 1.0000x reference)
//
#include <hip/hip_runtime.h>
#include <hip/hip_bf16.h>

#define S_TOK 8192
#define NEXP 64
#define NK 2048
#define CAP 256

// ---------------- K1: logits = x @ w^T, f32, split-K by 2 ----------------
// 256 blocks x 256 threads. Block = 64 tokens x 64 experts x 1024 ks.
// lane = token. Wave wv owns experts [16wv,16wv+16) in acc[16].
// W read via wave-uniform scalar loads in 16-k runs (s_load_dwordx16-able),
// expert-groups of 4 to bound live SGPRs.
// X tile in LDS as float4[64][32], col XOR-swizzled by (row&31):
// conflict-free b128 on both write (2 rows/wave, 32 distinct cols) and
// read (per-lane distinct col).
__global__ __launch_bounds__(256) void gemm_logits(const float* __restrict__ x,
                                                   const float* __restrict__ w,
                                                   float* __restrict__ part) {
    __shared__ float4 xs4[64 * 32];
    const int t = threadIdx.x;
    const int lane = t & 63;
    const int wv = __builtin_amdgcn_readfirstlane(t >> 6);  // 0..3
    const int e_base = wv * 16;
    const int tg = blockIdx.x & 127;     // token group
    const int kz = blockIdx.x >> 7;      // K half
    const int s0 = tg * 64;
    const int koff = kz * 1024;

    float acc[16];
#pragma unroll
    for (int j = 0; j < 16; ++j) acc[j] = 0.f;

    for (int k0 = 0; k0 < 1024; k0 += 128) {
        // stage x[64][128]: 2048 float4, 8 per thread
#pragma unroll
        for (int i = 0; i < 8; ++i) {
            int lin = t + i * 256;
            int row = lin >> 5;          // 0..63
            int c4  = lin & 31;          // logical float4 col
            float4 v = *reinterpret_cast<const float4*>(
                &x[(long long)(s0 + row) * NK + koff + k0 + c4 * 4]);
            xs4[row * 32 + (c4 ^ (row & 31))] = v;
        }
        __syncthreads();
#pragma unroll 2
        for (int kk = 0; kk < 128; kk += 16) {
            float xv[16];
            const int g0 = kk >> 2;
#pragma unroll
            for (int q = 0; q < 4; ++q)
                *reinterpret_cast<float4*>(&xv[q * 4]) =
                    xs4[lane * 32 + ((g0 + q) ^ (lane & 31))];
#pragma unroll
            for (int jg = 0; jg < 16; jg += 4) {
#pragma unroll
                for (int j = jg; j < jg + 4; ++j) {
                    const float* wr = w + (long long)(e_base + j) * NK + koff + k0 + kk;
#pragma unroll
                    for (int q = 0; q < 16; ++q)
                        acc[j] = fmaf(xv[q], wr[q], acc[j]);
                }
            }
        }
        __syncthreads();
    }
    float* dst = part + (long long)kz * (S_TOK * NEXP) + (long long)(s0 + lane) * NEXP + e_base;
    *reinterpret_cast<float4*>(&dst[0])  = make_float4(acc[0], acc[1], acc[2], acc[3]);
    *reinterpret_cast<float4*>(&dst[4])  = make_float4(acc[4], acc[5], acc[6], acc[7]);
    *reinterpret_cast<float4*>(&dst[8])  = make_float4(acc[8], acc[9], acc[10], acc[11]);
    *reinterpret_cast<float4*>(&dst[12]) = make_float4(acc[12], acc[13], acc[14], acc[15]);
}

// ---------------- K2: reduce K-halves + softmax gate + argmax ----------------
__global__ __launch_bounds__(256) void gate_argmax(const float* __restrict__ part,
                                                   int* __restrict__ eidx,
                                                   float* __restrict__ gate) {
    const int lane = threadIdx.x & 63;
    const int tok = blockIdx.x * 4 + (threadIdx.x >> 6);
    long long o = (long long)tok * NEXP + lane;
    float l = part[o] + part[(long long)(S_TOK * NEXP) + o];

    float m = l; int mi = lane;
#pragma unroll
    for (int off = 32; off; off >>= 1) {
        float om  = __shfl_xor(m, off);
        int   omi = __shfl_xor(mi, off);
        if (om > m || (om == m && omi < mi)) { m = om; mi = omi; }
    }
    float e = expf(l - m);
    float s = e;
#pragma unroll
    for (int off = 32; off; off >>= 1) s += __shfl_xor(s, off);

    if (lane == 0) {
        eidx[tok] = mi;
        gate[tok] = 1.0f / s;
    }
}

// ---------------- K3: per-expert rank (earliest tokens win) ----------------
__global__ __launch_bounds__(1024) void rank_tokens(const int* __restrict__ eidx,
                                                    int* __restrict__ pack) {
    __shared__ int cnts[16];
    const int e = blockIdx.x;
    const int t = threadIdx.x;
    const int lane = t & 63;
    const int v = __builtin_amdgcn_readfirstlane(t >> 6);   // strip 0..15
    const int base = v * 512;

    int cnt = 0;
#pragma unroll
    for (int i = 0; i < 8; ++i) {
        int s = base + i * 64 + lane;
        unsigned long long b = __ballot(eidx[s] == e);
        cnt += __popcll(b);
    }
    if (lane == 0) cnts[v] = cnt;
    __syncthreads();
    if (t == 0) {
        int run = 0;
#pragma unroll
        for (int j = 0; j < 16; ++j) { int c = cnts[j]; cnts[j] = run; run += c; }
    }
    __syncthreads();
    int run = cnts[v];
#pragma unroll
    for (int i = 0; i < 8; ++i) {
        int s = base + i * 64 + lane;
        bool m = (eidx[s] == e);
        unsigned long long b = __ballot(m);
        if (m) {
            int r = run + __popcll(b & ((1ull << lane) - 1ull));
            pack[s] = (r < CAP) ? ((r << 6) | e) : -1;
        }
        run += __popcll(b);
    }
}

// ---------------- K4: write the 1 GiB output in one streaming pass ----------------
// 4 consecutive (s,e) rows per wave -> 4 KiB contiguous per store stream
__global__ __launch_bounds__(256) void write_out(const int* __restrict__ pack,
                                                 const float* __restrict__ gate,
                                                 float* __restrict__ out) {
    const int t = threadIdx.x;
    const int lane = t & 63;
    const int wv = __builtin_amdgcn_readfirstlane(t >> 6);
    const int row0 = (blockIdx.x * 4 + wv) * 4;

#pragma unroll
    for (int r = 0; r < 4; ++r) {
        const int row = row0 + r;
        const int s = row >> 6;
        const int e = row & 63;
        const int info = pack[s];        // wave-uniform -> scalar load
        const float g = gate[s];

        float4 c4 = make_float4(0.f, 0.f, 0.f, 0.f);
        float4 d4 = make_float4(0.f, 0.f, 0.f, 0.f);
        if (info >= 0 && (info & 63) == e) {
            int rk = info >> 6;          // 0..255
            if ((rk >> 2) == lane) {
                ((float*)&c4)[rk & 3] = g;
                ((float*)&d4)[rk & 3] = 1.0f;
            }
        }
        long long o = (long long)row * CAP + lane * 4;
        *reinterpret_cast<float4*>(&out[o]) = c4;
        *reinterpret_cast<float4*>(&out[(long long)S_TOK * NEXP * CAP + o]) = d4;
    }
}

extern "C" void kernel_launch(void* const* d_in, const int* in_sizes, int n_in,
                              void* d_out, int out_size, void* d_ws, size_t ws_size,
                              hipStream_t stream) {
    const float* x = (const float*)d_in[0];   // [8192, 2048]
    const float* w = (const float*)d_in[1];   // [64, 2048]
    float* out = (float*)d_out;

    float* part = (float*)d_ws;                                   // 2 x 2 MiB split-K partials
    int*   eidx = (int*)((char*)d_ws + (size_t)2 * S_TOK * NEXP * 4);
    float* gate = (float*)((char*)eidx + (size_t)S_TOK * 4);
    int*   pack = (int*)((char*)gate + (size_t)S_TOK * 4);

    gemm_logits<<<256, 256, 0, stream>>>(x, w, part);
    gate_argmax<<<S_TOK / 4, 256, 0, stream>>>(part, eidx, gate);
    rank_tokens<<<NEXP, 1024, 0, stream>>>(eidx, pack);
    write_out<<<(S_TOK * NEXP) / 16, 256, 0, stream>>>(pack, gate, out);
}

// Round 5
// 1188.084 us; speedup vs baseline: 1.1903x; 1.1903x over previous
//
#include <hip/hip_runtime.h>
#include <hip/hip_bf16.h>

#define S_TOK 8192
#define NEXP 64
#define NK 2048
#define CAP 256

// ---------------- K1: logits = x @ w^T, f32, split-K by 4 ----------------
// 512 blocks x 256 threads = 2 blocks/CU (2 waves/SIMD, latency hiding).
// Block = 64 tokens x 64 experts x 512 ks. lane = token.
// Wave wv owns experts [16wv,16wv+16) in acc[16].
// W read via wave-uniform scalar loads (SGPR broadcast, no LDS for W).
// X staged in LDS [64][132].
__global__ __launch_bounds__(256) void gemm_logits(const float* __restrict__ x,
                                                   const float* __restrict__ w,
                                                   float* __restrict__ part) {
    __shared__ float xs[64][132];
    const int t = threadIdx.x;
    const int lane = t & 63;
    const int wv = __builtin_amdgcn_readfirstlane(t >> 6);  // 0..3
    const int e_base = wv * 16;
    const int tg = blockIdx.x & 127;     // token group
    const int kz = blockIdx.x >> 7;      // 0..3: K quarter
    const int s0 = tg * 64;
    const int koff = kz * 512;

    float acc[16];
#pragma unroll
    for (int j = 0; j < 16; ++j) acc[j] = 0.f;

    for (int k0 = 0; k0 < 512; k0 += 128) {
        // stage x[64][128]: 2048 float4, 8 per thread
#pragma unroll
        for (int i = 0; i < 8; ++i) {
            int lin = t + i * 256;
            int row = lin >> 5;          // 0..63
            int c4  = lin & 31;          // float4 within row
            float4 v = *reinterpret_cast<const float4*>(
                &x[(long long)(s0 + row) * NK + koff + k0 + c4 * 4]);
            *reinterpret_cast<float4*>(&xs[row][c4 * 4]) = v;
        }
        __syncthreads();
#pragma unroll 2
        for (int kk = 0; kk < 128; kk += 4) {
            float4 xv = *reinterpret_cast<const float4*>(&xs[lane][kk]);
#pragma unroll
            for (int j = 0; j < 16; ++j) {
                const float* wr = w + (long long)(e_base + j) * NK + koff + k0 + kk;
                acc[j] = fmaf(xv.x, wr[0], acc[j]);
                acc[j] = fmaf(xv.y, wr[1], acc[j]);
                acc[j] = fmaf(xv.z, wr[2], acc[j]);
                acc[j] = fmaf(xv.w, wr[3], acc[j]);
            }
        }
        __syncthreads();
    }
    float* dst = part + (long long)kz * (S_TOK * NEXP) + (long long)(s0 + lane) * NEXP + e_base;
    *reinterpret_cast<float4*>(&dst[0])  = make_float4(acc[0], acc[1], acc[2], acc[3]);
    *reinterpret_cast<float4*>(&dst[4])  = make_float4(acc[4], acc[5], acc[6], acc[7]);
    *reinterpret_cast<float4*>(&dst[8])  = make_float4(acc[8], acc[9], acc[10], acc[11]);
    *reinterpret_cast<float4*>(&dst[12]) = make_float4(acc[12], acc[13], acc[14], acc[15]);
}

// ---------------- K2: reduce K-quarters + softmax gate + argmax ----------------
// one wave (64 lanes = 64 experts) per token; 4 tokens per block
__global__ __launch_bounds__(256) void gate_argmax(const float* __restrict__ part,
                                                   int* __restrict__ eidx,
                                                   float* __restrict__ gate) {
    const int lane = threadIdx.x & 63;
    const int tok = blockIdx.x * 4 + (threadIdx.x >> 6);
    long long o = (long long)tok * NEXP + lane;
    const long long SE = (long long)S_TOK * NEXP;
    float l = (part[o] + part[SE + o]) + (part[2 * SE + o] + part[3 * SE + o]);

    float m = l; int mi = lane;
#pragma unroll
    for (int off = 32; off; off >>= 1) {
        float om  = __shfl_xor(m, off);
        int   omi = __shfl_xor(mi, off);
        if (om > m || (om == m && omi < mi)) { m = om; mi = omi; }
    }
    float e = expf(l - m);
    float s = e;
#pragma unroll
    for (int off = 32; off; off >>= 1) s += __shfl_xor(s, off);

    if (lane == 0) {
        eidx[tok] = mi;
        gate[tok] = 1.0f / s;
    }
}

// ---------------- K3: per-expert rank (earliest tokens win) ----------------
// 64 blocks (one per expert) x 1024 threads (16 waves, 512-token strips)
__global__ __launch_bounds__(1024) void rank_tokens(const int* __restrict__ eidx,
                                                    int* __restrict__ pack) {
    __shared__ int cnts[16];
    const int e = blockIdx.x;
    const int t = threadIdx.x;
    const int lane = t & 63;
    const int v = __builtin_amdgcn_readfirstlane(t >> 6);   // strip 0..15
    const int base = v * 512;

    int cnt = 0;
#pragma unroll
    for (int i = 0; i < 8; ++i) {
        int s = base + i * 64 + lane;
        unsigned long long b = __ballot(eidx[s] == e);
        cnt += __popcll(b);
    }
    if (lane == 0) cnts[v] = cnt;
    __syncthreads();
    if (t == 0) {
        int run = 0;
#pragma unroll
        for (int j = 0; j < 16; ++j) { int c = cnts[j]; cnts[j] = run; run += c; }
    }
    __syncthreads();
    int run = cnts[v];
#pragma unroll
    for (int i = 0; i < 8; ++i) {
        int s = base + i * 64 + lane;
        bool m = (eidx[s] == e);
        unsigned long long b = __ballot(m);
        if (m) {
            int r = run + __popcll(b & ((1ull << lane) - 1ull));
            pack[s] = (r < CAP) ? ((r << 6) | e) : -1;   // kept: rank+expert; dropped: -1
        }
        run += __popcll(b);
    }
}

// ---------------- K4: write the entire 1 GiB output in one pass ----------------
// one wave per (s,e) row of 256 capacity slots; 4 rows per 256-thread block
__global__ __launch_bounds__(256) void write_out(const int* __restrict__ pack,
                                                 const float* __restrict__ gate,
                                                 float* __restrict__ out) {
    const int t = threadIdx.x;
    const int lane = t & 63;
    const int wv = __builtin_amdgcn_readfirstlane(t >> 6);
    const int row = blockIdx.x * 4 + wv;    // (s,e) row index
    const int s = row >> 6;
    const int e = row & 63;

    const int info = pack[s];       // wave-uniform -> scalar load, L1-hot
    const float g = gate[s];

    float4 c4 = make_float4(0.f, 0.f, 0.f, 0.f);
    float4 d4 = make_float4(0.f, 0.f, 0.f, 0.f);
    if (info >= 0 && (info & 63) == e) {
        int r = info >> 6;          // 0..255
        if ((r >> 2) == lane) {
            ((float*)&c4)[r & 3] = g;
            ((float*)&d4)[r & 3] = 1.0f;
        }
    }
    long long o = (long long)row * CAP + lane * 4;
    *reinterpret_cast<float4*>(&out[o]) = c4;
    *reinterpret_cast<float4*>(&out[(long long)S_TOK * NEXP * CAP + o]) = d4;
}

extern "C" void kernel_launch(void* const* d_in, const int* in_sizes, int n_in,
                              void* d_out, int out_size, void* d_ws, size_t ws_size,
                              hipStream_t stream) {
    const float* x = (const float*)d_in[0];   // [8192, 2048]
    const float* w = (const float*)d_in[1];   // [64, 2048]
    float* out = (float*)d_out;

    // workspace layout
    float* part = (float*)d_ws;                                   // 4 x 2 MiB split-K partials
    int*   eidx = (int*)((char*)d_ws + (size_t)4 * S_TOK * NEXP * 4);
    float* gate = (float*)((char*)eidx + (size_t)S_TOK * 4);
    int*   pack = (int*)((char*)gate + (size_t)S_TOK * 4);

    gemm_logits<<<512, 256, 0, stream>>>(x, w, part);
    gate_argmax<<<S_TOK / 4, 256, 0, stream>>>(part, eidx, gate);
    rank_tokens<<<NEXP, 1024, 0, stream>>>(eidx, pack);
    write_out<<<(S_TOK * NEXP) / 4, 256, 0, stream>>>(pack, gate, out);
}